// Round 2
// baseline (292.968 us; speedup 1.0000x reference)
//
#include <hip/hip_runtime.h>
#include <math.h>

// Problem constants
#define B_    8
#define C_    192
#define N_    3136          // H*W
#define K_    9
#define C2_   384
#define OUT_  192
#define M_    (B_ * N_)     // 25088 rows
#define EPS_  1e-5f
#define NBLK_STATS 392      // 25088 / 64

typedef __bf16 bf16;
typedef __bf16 bf16x2 __attribute__((ext_vector_type(2)));
typedef __bf16 bf16x8 __attribute__((ext_vector_type(8)));
typedef float  f32x4  __attribute__((ext_vector_type(4)));

__device__ __forceinline__ float gelu_f(float x) {
    // exact GELU: 0.5*x*(1+erf(x/sqrt(2)))
    return 0.5f * x * (1.0f + erff(x * 0.70710678118654752440f));
}

// ---------------------------------------------------------------------------
// Cast helper: fp32 -> bf16, n elements
__global__ __launch_bounds__(256) void k_cast(const float* __restrict__ src,
                                              bf16* __restrict__ dst, int n) {
    const int i = blockIdx.x * 256 + threadIdx.x;
    if (i < n) dst[i] = (bf16)src[i];
}

// ---------------------------------------------------------------------------
// Kernel 1: x fp32 [B, C, N] -> xt bf16 [B, N, C]   (transpose via LDS tile)
// grid (N/64, C/32, B), block 256
__global__ __launch_bounds__(256) void k_transpose(const float* __restrict__ x,
                                                   bf16* __restrict__ xt) {
    __shared__ float T[32][65];   // +1 pad
    const int b  = blockIdx.z;
    const int c0 = blockIdx.y * 32;
    const int n0 = blockIdx.x * 64;
    const int tid = threadIdx.x;
    {   // read coalesced along n
        const int nl = tid & 63;
        const int cl = tid >> 6;          // 0..3
        #pragma unroll
        for (int r = 0; r < 8; ++r) {
            const int c = cl + r * 4;
            if (nl < 64) T[c][nl] = 0.f;  // placeholder to keep structure; overwritten below
            T[c][nl] = x[((size_t)b * C_ + (c0 + c)) * N_ + n0 + nl];
        }
    }
    __syncthreads();
    {   // write coalesced along c
        const int cl = tid & 31;
        const int nl = tid >> 5;          // 0..7
        #pragma unroll
        for (int r = 0; r < 8; ++r) {
            const int n = nl + r * 8;
            xt[((size_t)b * N_ + n0 + n) * C_ + c0 + cl] = (bf16)T[cl][n];
        }
    }
}

// ---------------------------------------------------------------------------
// Kernel 2: gather + max-diff + interleave -> feats [M, 2C] bf16
// feats[m, 2c] = x_c ; feats[m, 2c+1] = max_k( xt[j_k][c] - xt[i_k][c] )
// grid M blocks, block 192 (one thread per channel)
__global__ __launch_bounds__(192) void k_feats(const bf16* __restrict__ xt,
                                               const int* __restrict__ eidx,
                                               bf16* __restrict__ feats) {
    const int node = blockIdx.x;                // b*N + n
    const int b = node / N_;
    const int n = node - b * N_;
    const int c = threadIdx.x;
    const int* e0 = eidx + ((size_t)b * N_ + n) * K_;                 // edge_idx[0]
    const int* e1 = e0 + (size_t)B_ * N_ * K_;                        // edge_idx[1]
    const bf16* xb = xt + (size_t)b * N_ * C_;
    const float xv = (float)xb[(size_t)n * C_ + c];
    float mx = -1e30f;
    #pragma unroll
    for (int k = 0; k < K_; ++k) {
        const int j = e0[k];       // uniform per block -> scalar load
        const int i = e1[k];
        const float d = (float)xb[(size_t)j * C_ + c] - (float)xb[(size_t)i * C_ + c];
        mx = fmaxf(mx, d);
    }
    bf16x2 v; v[0] = (bf16)xv; v[1] = (bf16)mx;
    *(bf16x2*)&feats[(size_t)node * C2_ + 2 * c] = v;
}

// ---------------------------------------------------------------------------
// Kernel 3: GEMM1  h1[m,o] = sum_c feats[m,c]*w1[o,c] + b1[o]   (fp32 out)
// MFMA 16x16x32 bf16. Per wave: 16 rows x 64 cols. Block = 4 waves = 64x64.
// grid (M/64, C2/64), block 256
__global__ __launch_bounds__(256) void k_gemm1(const bf16* __restrict__ A,
                                               const bf16* __restrict__ W,
                                               const float* __restrict__ bias,
                                               float* __restrict__ Hout) {
    const int lane  = threadIdx.x & 63;
    const int wv    = threadIdx.x >> 6;
    const int m0    = blockIdx.x * 64 + wv * 16;
    const int n0    = blockIdx.y * 64;
    const int l16   = lane & 15;
    const int quad  = lane >> 4;
    const bf16* arow = A + (size_t)(m0 + l16) * C2_ + quad * 8;
    const bf16* wrow = W + (size_t)(n0 + l16) * C2_ + quad * 8;
    f32x4 acc[4] = {{0,0,0,0},{0,0,0,0},{0,0,0,0},{0,0,0,0}};
    #pragma unroll
    for (int kk = 0; kk < C2_; kk += 32) {
        const bf16x8 a = *(const bf16x8*)(arow + kk);
        #pragma unroll
        for (int nf = 0; nf < 4; ++nf) {
            const bf16x8 bfr = *(const bf16x8*)(wrow + (size_t)nf * 16 * C2_ + kk);
            acc[nf] = __builtin_amdgcn_mfma_f32_16x16x32_bf16(a, bfr, acc[nf], 0, 0, 0);
        }
    }
    // C/D layout: col = lane&15, row = quad*4 + reg
    #pragma unroll
    for (int nf = 0; nf < 4; ++nf) {
        const int col = n0 + nf * 16 + l16;
        const float bv = bias[col];
        #pragma unroll
        for (int r = 0; r < 4; ++r) {
            Hout[(size_t)(m0 + quad * 4 + r) * C2_ + col] = acc[nf][r] + bv;
        }
    }
}

// ---------------------------------------------------------------------------
// Stats: per-column partial sum / sumsq over 64-row chunks. grid 392, block NC
template <int NC>
__global__ void k_stats(const float* __restrict__ Hm,
                        float* __restrict__ psum, float* __restrict__ psq) {
    const int c  = threadIdx.x;
    const int r0 = blockIdx.x * 64;
    float s = 0.f, q = 0.f;
    for (int r = 0; r < 64; ++r) {
        const float v = Hm[(size_t)(r0 + r) * NC + c];
        s += v; q += v * v;
    }
    psum[(size_t)blockIdx.x * NC + c] = s;
    psq [(size_t)blockIdx.x * NC + c] = q;
}

// Finalize: mean/var -> scale/shift. 1 block of NC threads.
template <int NC>
__global__ void k_finalize(const float* __restrict__ psum, const float* __restrict__ psq,
                           const float* __restrict__ g, const float* __restrict__ beta,
                           float* __restrict__ sc, float* __restrict__ sh) {
    const int c = threadIdx.x;
    float s = 0.f, q = 0.f;
    for (int pb = 0; pb < NBLK_STATS; ++pb) {
        s += psum[(size_t)pb * NC + c];
        q += psq [(size_t)pb * NC + c];
    }
    const float mean = s / (float)M_;
    const float var  = q / (float)M_ - mean * mean;   // biased (ddof=0)
    const float inv  = rsqrtf(var + EPS_);
    const float scale = g[c] * inv;
    sc[c] = scale;
    sh[c] = beta[c] - mean * scale;
}

// ---------------------------------------------------------------------------
// Kernel 6: GEMM2 with BN1+GELU fused on the A operand.
// h2[m,o] = sum_c gelu(h1[m,c]*sc1[c]+sh1[c]) * w2[o,c] + b2[o]
// grid (M/64, OUT/64), block 256
__global__ __launch_bounds__(256) void k_gemm2(const float* __restrict__ H1,
                                               const bf16* __restrict__ W2,
                                               const float* __restrict__ bias2,
                                               const float* __restrict__ sc,
                                               const float* __restrict__ sh,
                                               float* __restrict__ H2) {
    __shared__ float s_sc[C2_], s_sh[C2_];
    for (int i = threadIdx.x; i < C2_; i += 256) { s_sc[i] = sc[i]; s_sh[i] = sh[i]; }
    __syncthreads();
    const int lane  = threadIdx.x & 63;
    const int wv    = threadIdx.x >> 6;
    const int m0    = blockIdx.x * 64 + wv * 16;
    const int n0    = blockIdx.y * 64;
    const int l16   = lane & 15;
    const int quad  = lane >> 4;
    const float* arow = H1 + (size_t)(m0 + l16) * C2_ + quad * 8;
    const bf16* wrow  = W2 + (size_t)(n0 + l16) * C2_ + quad * 8;
    f32x4 acc[4] = {{0,0,0,0},{0,0,0,0},{0,0,0,0},{0,0,0,0}};
    #pragma unroll
    for (int kk = 0; kk < C2_; kk += 32) {
        const int kb = kk + quad * 8;
        const float4 x0 = *(const float4*)(arow + kk);
        const float4 x1 = *(const float4*)(arow + kk + 4);
        float xs[8] = {x0.x, x0.y, x0.z, x0.w, x1.x, x1.y, x1.z, x1.w};
        bf16x8 a;
        #pragma unroll
        for (int j = 0; j < 8; ++j) {
            const float y = fmaf(xs[j], s_sc[kb + j], s_sh[kb + j]);
            a[j] = (bf16)gelu_f(y);
        }
        #pragma unroll
        for (int nf = 0; nf < 4; ++nf) {
            const bf16x8 bfr = *(const bf16x8*)(wrow + (size_t)nf * 16 * C2_ + kk);
            acc[nf] = __builtin_amdgcn_mfma_f32_16x16x32_bf16(a, bfr, acc[nf], 0, 0, 0);
        }
    }
    #pragma unroll
    for (int nf = 0; nf < 4; ++nf) {
        const int col = n0 + nf * 16 + l16;
        const float bv = bias2[col];
        #pragma unroll
        for (int r = 0; r < 4; ++r) {
            H2[(size_t)(m0 + quad * 4 + r) * OUT_ + col] = acc[nf][r] + bv;
        }
    }
}

// ---------------------------------------------------------------------------
// Kernel 9: BN2+GELU + transpose [M, OUT] -> out fp32 [B, OUT, N]
// grid (N/64, OUT/32, B), block 256
__global__ __launch_bounds__(256) void k_out(const float* __restrict__ H2,
                                             const float* __restrict__ sc,
                                             const float* __restrict__ sh,
                                             float* __restrict__ out) {
    __shared__ float T[64][33];
    const int b  = blockIdx.z;
    const int o0 = blockIdx.y * 32;
    const int n0 = blockIdx.x * 64;
    const int tid = threadIdx.x;
    {   // read coalesced along o, apply BN+GELU
        const int ol = tid & 31;
        const int nl = tid >> 5;   // 0..7
        const float scale = sc[o0 + ol];
        const float shift = sh[o0 + ol];
        #pragma unroll
        for (int r = 0; r < 8; ++r) {
            const int n = nl + r * 8;
            const float v = H2[((size_t)b * N_ + n0 + n) * OUT_ + o0 + ol];
            T[n][ol] = gelu_f(fmaf(v, scale, shift));
        }
    }
    __syncthreads();
    {   // write coalesced along n
        const int nl = tid & 63;
        const int ol = tid >> 6;   // 0..3
        #pragma unroll
        for (int r = 0; r < 8; ++r) {
            const int o = ol + r * 4;
            out[((size_t)b * OUT_ + o0 + o) * N_ + n0 + nl] = T[nl][o];
        }
    }
}

// ---------------------------------------------------------------------------
extern "C" void kernel_launch(void* const* d_in, const int* in_sizes, int n_in,
                              void* d_out, int out_size, void* d_ws, size_t ws_size,
                              hipStream_t stream) {
    const float* x     = (const float*)d_in[0];
    const int*   eidx  = (const int*)  d_in[1];
    const float* w1    = (const float*)d_in[2];
    const float* b1    = (const float*)d_in[3];
    const float* g1    = (const float*)d_in[4];
    const float* beta1 = (const float*)d_in[5];
    const float* w2    = (const float*)d_in[6];
    const float* b2    = (const float*)d_in[7];
    const float* g2    = (const float*)d_in[8];
    const float* beta2 = (const float*)d_in[9];
    float* out = (float*)d_out;

    // workspace layout (all offsets multiples of 16B)
    char* ws = (char*)d_ws;
    size_t off = 0;
    bf16*  xt    = (bf16*)(ws + off); off += (size_t)M_ * C_  * sizeof(bf16);   // 9.6 MB
    bf16*  feats = (bf16*)(ws + off); off += (size_t)M_ * C2_ * sizeof(bf16);   // 19.3 MB
    float* h1    = (float*)(ws + off); off += (size_t)M_ * C2_ * sizeof(float); // 38.5 MB
    float* h2    = (float*)(ws + off); off += (size_t)M_ * OUT_ * sizeof(float);// 19.3 MB
    bf16*  w1b   = (bf16*)(ws + off); off += (size_t)C2_ * C2_ * sizeof(bf16);
    bf16*  w2b   = (bf16*)(ws + off); off += (size_t)OUT_ * C2_ * sizeof(bf16);
    float* p1s   = (float*)(ws + off); off += (size_t)NBLK_STATS * C2_ * sizeof(float);
    float* p1q   = (float*)(ws + off); off += (size_t)NBLK_STATS * C2_ * sizeof(float);
    float* p2s   = (float*)(ws + off); off += (size_t)NBLK_STATS * OUT_ * sizeof(float);
    float* p2q   = (float*)(ws + off); off += (size_t)NBLK_STATS * OUT_ * sizeof(float);
    float* sc1   = (float*)(ws + off); off += 512 * sizeof(float);
    float* sh1   = (float*)(ws + off); off += 512 * sizeof(float);
    float* sc2   = (float*)(ws + off); off += 512 * sizeof(float);
    float* sh2   = (float*)(ws + off); off += 512 * sizeof(float);

    k_cast<<<(C2_ * C2_ + 255) / 256, 256, 0, stream>>>(w1, w1b, C2_ * C2_);
    k_cast<<<(OUT_ * C2_ + 255) / 256, 256, 0, stream>>>(w2, w2b, OUT_ * C2_);
    k_transpose<<<dim3(N_ / 64, C_ / 32, B_), 256, 0, stream>>>(x, xt);
    k_feats<<<M_, 192, 0, stream>>>(xt, eidx, feats);
    k_gemm1<<<dim3(M_ / 64, C2_ / 64), 256, 0, stream>>>(feats, w1b, b1, h1);
    k_stats<C2_><<<NBLK_STATS, C2_, 0, stream>>>(h1, p1s, p1q);
    k_finalize<C2_><<<1, C2_, 0, stream>>>(p1s, p1q, g1, beta1, sc1, sh1);
    k_gemm2<<<dim3(M_ / 64, OUT_ / 64), 256, 0, stream>>>(h1, w2b, b2, sc1, sh1, h2);
    k_stats<OUT_><<<NBLK_STATS, OUT_, 0, stream>>>(h2, p2s, p2q);
    k_finalize<OUT_><<<1, OUT_, 0, stream>>>(p2s, p2q, g2, beta2, sc2, sh2);
    k_out<<<dim3(N_ / 64, OUT_ / 32, B_), 256, 0, stream>>>(h2, sc2, sh2, out);
}

// Round 3
// 178.341 us; speedup vs baseline: 1.6427x; 1.6427x over previous
//
#include <hip/hip_runtime.h>
#include <math.h>

// Problem constants
#define B_    8
#define C_    192
#define N_    3136          // H*W
#define K_    9
#define C2_   384
#define OUT_  192
#define M_    (B_ * N_)     // 25088 rows
#define EPS_  1e-5f

typedef __bf16 bf16;
typedef __bf16 bf16x8 __attribute__((ext_vector_type(8)));
typedef float  f32x4  __attribute__((ext_vector_type(4)));

__device__ __forceinline__ float gelu_f(float x) {
    return 0.5f * x * (1.0f + erff(x * 0.70710678118654752440f));
}

// async global->LDS, 16B per lane; lds base must be wave-uniform
__device__ __forceinline__ void gl_lds16(const void* g, void* l) {
    __builtin_amdgcn_global_load_lds(
        (const __attribute__((address_space(1))) unsigned int*)g,
        (__attribute__((address_space(3))) unsigned int*)l, 16, 0, 0);
}

// ---------------------------------------------------------------------------
// Prep: cast+permute w1 -> w1p (de-interleave input cols), cast w2, zero stats.
// w1p[o][c] = w1[o][2c] (c<192) ; w1p[o][192+c] = w1[o][2c+1]
// grid 576 x 256 (covers 147456 = C2*C2)
__global__ __launch_bounds__(256) void k_prep(const float* __restrict__ w1,
                                              const float* __restrict__ w2,
                                              bf16* __restrict__ w1p,
                                              bf16* __restrict__ w2b,
                                              float* __restrict__ stats) {
    const int idx = blockIdx.x * 256 + threadIdx.x;
    if (idx < C2_ * C2_) {
        const int o  = idx / C2_;
        const int cc = idx - o * C2_;
        const int src = (cc < C_) ? (2 * cc) : (2 * (cc - C_) + 1);
        w1p[idx] = (bf16)w1[o * C2_ + src];
    }
    if (idx < OUT_ * C2_) w2b[idx] = (bf16)w2[idx];
    if (idx < 1152) stats[idx] = 0.f;   // p1s[384] p1q[384] p2s[192] p2q[192]
}

// ---------------------------------------------------------------------------
// Transpose: x fp32 [B, C, N] -> xt bf16 [B, N, C]
// grid (N/64, C/32, B), block 256
__global__ __launch_bounds__(256) void k_transpose(const float* __restrict__ x,
                                                   bf16* __restrict__ xt) {
    __shared__ float T[32][65];
    const int b  = blockIdx.z;
    const int c0 = blockIdx.y * 32;
    const int n0 = blockIdx.x * 64;
    const int tid = threadIdx.x;
    {
        const int nl = tid & 63;
        const int cl = tid >> 6;
        #pragma unroll
        for (int r = 0; r < 8; ++r) {
            const int c = cl + r * 4;
            T[c][nl] = x[((size_t)b * C_ + (c0 + c)) * N_ + n0 + nl];
        }
    }
    __syncthreads();
    {
        const int cl = tid & 31;
        const int nl = tid >> 5;
        #pragma unroll
        for (int r = 0; r < 8; ++r) {
            const int n = nl + r * 8;
            xt[((size_t)b * N_ + n0 + n) * C_ + c0 + cl] = (bf16)T[cl][n];
        }
    }
}

// ---------------------------------------------------------------------------
// Feats (diff half only): d[node][c] = max_k( xt[j_k][c] - xt[i_k][c] )
// grid M, block 192
__global__ __launch_bounds__(192) void k_feats(const bf16* __restrict__ xt,
                                               const int* __restrict__ eidx,
                                               bf16* __restrict__ dbuf) {
    const int node = blockIdx.x;
    const int b = node / N_;
    const int c = threadIdx.x;
    const int* e0 = eidx + (size_t)node * K_;
    const int* e1 = e0 + (size_t)M_ * K_;
    const bf16* xb = xt + (size_t)b * N_ * C_;
    float mx = -1e30f;
    #pragma unroll
    for (int k = 0; k < K_; ++k) {
        const int j = e0[k];
        const int i = e1[k];
        mx = fmaxf(mx, (float)xb[(size_t)j * C_ + c] - (float)xb[(size_t)i * C_ + c]);
    }
    dbuf[(size_t)node * C_ + c] = (bf16)mx;
}

// ---------------------------------------------------------------------------
// GEMM1: h1[m,o] = sum_c [X|D][m,c] * w1p[o,c] + b1[o]  -> bf16, fused stats
// 128x128 block tile, BK=32, 4 waves each 64x64 (4x4 frags of 16x16x32)
// grid (196, 3), block 256
__global__ __launch_bounds__(256) void k_gemm1(const bf16* __restrict__ X,
                                               const bf16* __restrict__ D,
                                               const bf16* __restrict__ Wp,
                                               const float* __restrict__ bias,
                                               bf16* __restrict__ H1,
                                               float* __restrict__ psum,
                                               float* __restrict__ psq) {
    __shared__ bf16 As[128 * 32];
    __shared__ bf16 Bs[128 * 32];
    const int tid  = threadIdx.x;
    const int lane = tid & 63;
    const int wv   = tid >> 6;
    const int l16  = lane & 15;
    const int quad = lane >> 4;
    const int m0   = blockIdx.x * 128;
    const int n0   = blockIdx.y * 128;
    const int srow = lane >> 2;        // 0..15
    const int scol = (lane & 3) * 8;   // 0,8,16,24
    const int wm   = (wv & 1) * 64;
    const int wn   = (wv >> 1) * 64;

    f32x4 acc[4][4] = {};

    for (int kk = 0; kk < C2_; kk += 32) {
        __syncthreads();
        // stage A (rows wv*32..wv*32+31) from X (kk<192) or D
        const bf16* asrc = (kk < C_) ? X : D;
        const int   kcol = (kk < C_) ? kk : (kk - C_);
        #pragma unroll
        for (int h = 0; h < 2; ++h) {
            const int r = wv * 32 + h * 16;
            gl_lds16(asrc + (size_t)(m0 + r + srow) * C_ + kcol + scol,
                     &As[r * 32]);
            gl_lds16(Wp + (size_t)(n0 + r + srow) * C2_ + kk + scol,
                     &Bs[r * 32]);
        }
        __syncthreads();
        bf16x8 af[4], bf[4];
        #pragma unroll
        for (int f = 0; f < 4; ++f) {
            af[f] = *(const bf16x8*)&As[(wm + f * 16 + l16) * 32 + quad * 8];
            bf[f] = *(const bf16x8*)&Bs[(wn + f * 16 + l16) * 32 + quad * 8];
        }
        #pragma unroll
        for (int mf = 0; mf < 4; ++mf)
            #pragma unroll
            for (int nf = 0; nf < 4; ++nf)
                acc[mf][nf] = __builtin_amdgcn_mfma_f32_16x16x32_bf16(
                    af[mf], bf[nf], acc[mf][nf], 0, 0, 0);
    }

    // epilogue: bias, bf16 store, fused per-column stats
    #pragma unroll
    for (int nf = 0; nf < 4; ++nf) {
        const int col = n0 + wn + nf * 16 + l16;
        const float bv = bias[col];
        float s = 0.f, q = 0.f;
        #pragma unroll
        for (int mf = 0; mf < 4; ++mf) {
            #pragma unroll
            for (int r = 0; r < 4; ++r) {
                const float v = acc[mf][nf][r] + bv;
                s += v; q += v * v;
                H1[(size_t)(m0 + wm + mf * 16 + quad * 4 + r) * C2_ + col] = (bf16)v;
            }
        }
        s += __shfl_xor(s, 16); s += __shfl_xor(s, 32);
        q += __shfl_xor(q, 16); q += __shfl_xor(q, 32);
        if (quad == 0) { atomicAdd(&psum[col], s); atomicAdd(&psq[col], q); }
    }
}

// ---------------------------------------------------------------------------
// Finalize BN params from accumulated stats
template <int NC>
__global__ void k_finalize(const float* __restrict__ psum, const float* __restrict__ psq,
                           const float* __restrict__ g, const float* __restrict__ beta,
                           float* __restrict__ sc, float* __restrict__ sh) {
    const int c = threadIdx.x;
    const float mean = psum[c] / (float)M_;
    const float var  = psq[c] / (float)M_ - mean * mean;
    const float inv  = rsqrtf(var + EPS_);
    const float scale = g[c] * inv;
    sc[c] = scale;
    sh[c] = beta[c] - mean * scale;
}

// ---------------------------------------------------------------------------
// Activation: a1 = bf16(gelu(h1*sc + sh)), elementwise over [M,384]
// grid 4704 x 256, 8 elems/thread
__global__ __launch_bounds__(256) void k_act(const bf16* __restrict__ H1,
                                             const float* __restrict__ sc,
                                             const float* __restrict__ sh,
                                             bf16* __restrict__ A1) {
    const size_t i8 = ((size_t)blockIdx.x * 256 + threadIdx.x) * 8;
    const int c0 = (int)(i8 % C2_);
    const bf16x8 v = *(const bf16x8*)&H1[i8];
    const float4 sca = *(const float4*)&sc[c0];
    const float4 scb = *(const float4*)&sc[c0 + 4];
    const float4 sha = *(const float4*)&sh[c0];
    const float4 shb = *(const float4*)&sh[c0 + 4];
    const float scs[8] = {sca.x, sca.y, sca.z, sca.w, scb.x, scb.y, scb.z, scb.w};
    const float shs[8] = {sha.x, sha.y, sha.z, sha.w, shb.x, shb.y, shb.z, shb.w};
    bf16x8 o;
    #pragma unroll
    for (int j = 0; j < 8; ++j)
        o[j] = (bf16)gelu_f(fmaf((float)v[j], scs[j], shs[j]));
    *(bf16x8*)&A1[i8] = o;
}

// ---------------------------------------------------------------------------
// GEMM2: h2[m,o] = sum_c a1[m,c]*w2[o,c] + b2[o] -> bf16, fused stats
// 128x64 block tile, BK=32, 4 waves each 64x32 (4x2 frags)
// grid (196, 3), block 256
__global__ __launch_bounds__(256) void k_gemm2(const bf16* __restrict__ A1,
                                               const bf16* __restrict__ W2,
                                               const float* __restrict__ bias,
                                               bf16* __restrict__ H2,
                                               float* __restrict__ psum,
                                               float* __restrict__ psq) {
    __shared__ bf16 As[128 * 32];
    __shared__ bf16 Bs[64 * 32];
    const int tid  = threadIdx.x;
    const int lane = tid & 63;
    const int wv   = tid >> 6;
    const int l16  = lane & 15;
    const int quad = lane >> 4;
    const int m0   = blockIdx.x * 128;
    const int n0   = blockIdx.y * 64;
    const int srow = lane >> 2;
    const int scol = (lane & 3) * 8;
    const int wm   = (wv & 1) * 64;
    const int wn   = (wv >> 1) * 32;

    f32x4 acc[4][2] = {};

    for (int kk = 0; kk < C2_; kk += 32) {
        __syncthreads();
        #pragma unroll
        for (int h = 0; h < 2; ++h) {
            const int r = wv * 32 + h * 16;
            gl_lds16(A1 + (size_t)(m0 + r + srow) * C2_ + kk + scol,
                     &As[r * 32]);
        }
        {   // B: 64 rows, wave wv stages rows wv*16..wv*16+15
            const int r = wv * 16;
            gl_lds16(W2 + (size_t)(n0 + r + srow) * C2_ + kk + scol,
                     &Bs[r * 32]);
        }
        __syncthreads();
        bf16x8 af[4], bf[2];
        #pragma unroll
        for (int f = 0; f < 4; ++f)
            af[f] = *(const bf16x8*)&As[(wm + f * 16 + l16) * 32 + quad * 8];
        #pragma unroll
        for (int f = 0; f < 2; ++f)
            bf[f] = *(const bf16x8*)&Bs[(wn + f * 16 + l16) * 32 + quad * 8];
        #pragma unroll
        for (int mf = 0; mf < 4; ++mf)
            #pragma unroll
            for (int nf = 0; nf < 2; ++nf)
                acc[mf][nf] = __builtin_amdgcn_mfma_f32_16x16x32_bf16(
                    af[mf], bf[nf], acc[mf][nf], 0, 0, 0);
    }

    #pragma unroll
    for (int nf = 0; nf < 2; ++nf) {
        const int col = n0 + wn + nf * 16 + l16;
        const float bv = bias[col];
        float s = 0.f, q = 0.f;
        #pragma unroll
        for (int mf = 0; mf < 4; ++mf) {
            #pragma unroll
            for (int r = 0; r < 4; ++r) {
                const float v = acc[mf][nf][r] + bv;
                s += v; q += v * v;
                H2[(size_t)(m0 + wm + mf * 16 + quad * 4 + r) * OUT_ + col] = (bf16)v;
            }
        }
        s += __shfl_xor(s, 16); s += __shfl_xor(s, 32);
        q += __shfl_xor(q, 16); q += __shfl_xor(q, 32);
        if (quad == 0) { atomicAdd(&psum[col], s); atomicAdd(&psq[col], q); }
    }
}

// ---------------------------------------------------------------------------
// Output: BN2+GELU + transpose [M, OUT] bf16 -> out fp32 [B, OUT, N]
// grid (N/64, OUT/32, B), block 256
__global__ __launch_bounds__(256) void k_out(const bf16* __restrict__ H2,
                                             const float* __restrict__ sc,
                                             const float* __restrict__ sh,
                                             float* __restrict__ out) {
    __shared__ float T[64][33];
    const int b  = blockIdx.z;
    const int o0 = blockIdx.y * 32;
    const int n0 = blockIdx.x * 64;
    const int tid = threadIdx.x;
    {
        const int ol = tid & 31;
        const int nl = tid >> 5;
        const float scale = sc[o0 + ol];
        const float shift = sh[o0 + ol];
        #pragma unroll
        for (int r = 0; r < 8; ++r) {
            const int n = nl + r * 8;
            const float v = (float)H2[((size_t)b * N_ + n0 + n) * OUT_ + o0 + ol];
            T[n][ol] = gelu_f(fmaf(v, scale, shift));
        }
    }
    __syncthreads();
    {
        const int nl = tid & 63;
        const int ol = tid >> 6;
        #pragma unroll
        for (int r = 0; r < 8; ++r) {
            const int o = ol + r * 4;
            out[((size_t)b * OUT_ + o0 + o) * N_ + n0 + nl] = T[nl][o];
        }
    }
}

// ---------------------------------------------------------------------------
extern "C" void kernel_launch(void* const* d_in, const int* in_sizes, int n_in,
                              void* d_out, int out_size, void* d_ws, size_t ws_size,
                              hipStream_t stream) {
    const float* x     = (const float*)d_in[0];
    const int*   eidx  = (const int*)  d_in[1];
    const float* w1    = (const float*)d_in[2];
    const float* b1    = (const float*)d_in[3];
    const float* g1    = (const float*)d_in[4];
    const float* beta1 = (const float*)d_in[5];
    const float* w2    = (const float*)d_in[6];
    const float* b2    = (const float*)d_in[7];
    const float* g2    = (const float*)d_in[8];
    const float* beta2 = (const float*)d_in[9];
    float* out = (float*)d_out;

    char* ws = (char*)d_ws;
    size_t off = 0;
    bf16*  xt    = (bf16*)(ws + off); off += (size_t)M_ * C_  * sizeof(bf16);   // 9.6 MB
    bf16*  dbuf  = (bf16*)(ws + off); off += (size_t)M_ * C_  * sizeof(bf16);   // 9.6 MB
    bf16*  h1    = (bf16*)(ws + off); off += (size_t)M_ * C2_ * sizeof(bf16);   // 19.3 MB
    bf16*  a1    = (bf16*)(ws + off); off += (size_t)M_ * C2_ * sizeof(bf16);   // 19.3 MB
    bf16*  h2    = (bf16*)(ws + off); off += (size_t)M_ * OUT_ * sizeof(bf16);  // 9.6 MB
    bf16*  w1p   = (bf16*)(ws + off); off += (size_t)C2_ * C2_ * sizeof(bf16);
    bf16*  w2b   = (bf16*)(ws + off); off += (size_t)OUT_ * C2_ * sizeof(bf16);
    float* stats = (float*)(ws + off); off += 1152 * sizeof(float);
    float* p1s = stats;        // 384
    float* p1q = stats + 384;  // 384
    float* p2s = stats + 768;  // 192
    float* p2q = stats + 960;  // 192
    float* sc1   = (float*)(ws + off); off += 512 * sizeof(float);
    float* sh1   = (float*)(ws + off); off += 512 * sizeof(float);
    float* sc2   = (float*)(ws + off); off += 512 * sizeof(float);
    float* sh2   = (float*)(ws + off); off += 512 * sizeof(float);

    k_prep<<<576, 256, 0, stream>>>(w1, w2, w1p, w2b, stats);
    k_transpose<<<dim3(N_ / 64, C_ / 32, B_), 256, 0, stream>>>(x, xt);
    k_feats<<<M_, 192, 0, stream>>>(xt, eidx, dbuf);
    k_gemm1<<<dim3(M_ / 128, C2_ / 128), 256, 0, stream>>>(xt, dbuf, w1p, b1, h1, p1s, p1q);
    k_finalize<C2_><<<1, C2_, 0, stream>>>(p1s, p1q, g1, beta1, sc1, sh1);
    k_act<<<4704, 256, 0, stream>>>(h1, sc1, sh1, a1);
    k_gemm2<<<dim3(M_ / 128, OUT_ / 64), 256, 0, stream>>>(a1, w2b, b2, h2, p2s, p2q);
    k_finalize<OUT_><<<1, OUT_, 0, stream>>>(p2s, p2q, g2, beta2, sc2, sh2);
    k_out<<<dim3(N_ / 64, OUT_ / 32, B_), 256, 0, stream>>>(h2, sc2, sh2, out);
}